// Round 2
// baseline (398.725 us; speedup 1.0000x reference)
//
#include <hip/hip_runtime.h>
#include <math.h>

// Fused LSTM, bf16 MFMA, BARRIER-FREE recurrent loop (round 10).
// B=1024,T=256,D=128,H=64,G=256,O=128. 256 blocks x 256 thr (4 waves).
// EACH WAVE OWNS ONE BATCH (b = 4*blk + w): no cross-wave data flow in the
// t-loop -> zero s_barrier in 256 steps (R8/R9 paid 256+ barriers; profile
// showed identical MFMA busy time but +300cy/step stall in lockstep waves).
// Per step: wave computes all 256 gate cols: 16 col-tiles x (K=64 -> 2
// chained 16x16x32 MFMAs) = 32 MFMA, M-rows = h replicas. h exchange =
// wave-private LDS round trip (in-order per wave, lgkmcnt only).
// gx: per 16-step chunk, MFMA with M=16 timesteps (A rows = ts), Wih bf16
// in block-shared LDS (granule-XOR swizzled), output round-tripped via
// wave-private gxlds into 64 regs (gxq), bias folded at readback.
// C-init trick: lane (qd,lq) owns cell j=16qd+lq; gate q lives in tile
// 4q+qd at D[row 4qd][col lq] = that lane's acc reg0 -> set C reg0 = gx
// (valid for every consumer lane; other rows junk), extract reg0 with a
// 2-level cndmask select over qd. Persistent acc quads: only reg0 is
// re-initialized each step (junk rows accumulate harmlessly, bounded).
constexpr int B = 1024, T = 256, D = 128, H = 64, O = 128;
constexpr int BQ = 4;            // batches per block = waves per block
constexpr int NBLK = B / BQ;     // 256 blocks
constexpr int TC = 16;           // timesteps per chunk (= MFMA M dim)
constexpr int NCH = T / TC;      // 16 chunks

typedef __attribute__((ext_vector_type(8))) short short8;
typedef __attribute__((ext_vector_type(4))) float f32x4;

__device__ __forceinline__ unsigned short f2bf(float f) {
    union { float f; unsigned u; } v; v.f = f;
    return (unsigned short)((v.u + 0x7FFF + ((v.u >> 16) & 1)) >> 16);  // RNE
}
__device__ __forceinline__ float frcp(float x) { return __builtin_amdgcn_rcpf(x); }
__device__ __forceinline__ float sigmoidf_(float x) {
    return frcp(1.0f + __expf(-x));
}
__device__ __forceinline__ float tanhf_(float x) {
    return fmaf(2.0f, frcp(1.0f + __expf(-2.0f * x)), -1.0f);  // overflow-safe
}

__global__ __launch_bounds__(256, 1)
void lstm_fused(const float* __restrict__ x, const float* __restrict__ Wih,
                const float* __restrict__ Whh, const float* __restrict__ bih,
                const float* __restrict__ bhh, const float* __restrict__ Wo,
                const float* __restrict__ bo, float* __restrict__ out)
{
    // Wih bf16, B-fragment granules: granule (n,kg) = Wih[n][8kg..8kg+7] at
    // byte n*256 + ((kg ^ (n&15))<<4)  -> burst reads are conflict-optimal.
    __shared__ unsigned short wihlds[256 * 128];   // 64 KB (block-shared)
    // per-wave gx scratch: [tile 0..15][lq 0..15 (stride 20)][ts 0..15]
    __shared__ float gxlds[4][16 * 320];           // 80 KB
    __shared__ unsigned short hlds[4][64];         // 512 B (wave-private h)
    __shared__ float hfin[4][64];                  // 1 KB (epilogue)

    const int tid  = threadIdx.x;
    const int lane = tid & 63;
    const int w    = tid >> 6;
    const int lq   = lane & 15;
    const int qd   = lane >> 4;
    const int b    = blockIdx.x * BQ + w;          // this wave's batch

    // ---- stage Wih -> LDS (bf16, swizzled granules), coalesced ----
    #pragma unroll
    for (int i = 0; i < 16; ++i) {
        int gid = i * 256 + tid;
        int n = gid >> 4, kg = gid & 15;
        const float* p = Wih + (size_t)n * D + 8 * kg;
        short8 v;
        #pragma unroll
        for (int j = 0; j < 8; ++j) v[j] = (short)f2bf(p[j]);
        *(short8*)((char*)wihlds + n * 256 + ((kg ^ (n & 15)) << 4)) = v;
    }

    // ---- Whh B-fragments in registers: whh_f[tile][c] (128 VGPRs) ----
    short8 whh_f[16][2];
    #pragma unroll
    for (int t16 = 0; t16 < 16; ++t16)
        #pragma unroll
        for (int c = 0; c < 2; ++c) {
            const float* p = Whh + (size_t)(16 * t16 + lq) * H + 32 * c + 8 * qd;
            short8 v;
            #pragma unroll
            for (int j = 0; j < 8; ++j) v[j] = (short)f2bf(p[j]);
            whh_f[t16][c] = v;
        }

    // ---- per-cell bias (cell j = 16*qd + lq) ----
    float bias4[4];
    #pragma unroll
    for (int q = 0; q < 4; ++q) {
        int n = 64 * q + 16 * qd + lq;
        bias4[q] = bih[n] + bhh[n];
    }

    __syncthreads();   // the ONLY block barrier: wihlds ready

    // ---- x prefetch: lane (qd,lq) supplies A[m=lq][k=32c+8qd..+7] ----
    const float* xb = x + (size_t)b * T * D + (size_t)lq * D + 8 * qd;
    float4 pf[8];
    auto issue_pf = [&](int t0) {
        #pragma unroll
        for (int c = 0; c < 4; ++c) {
            const float* p = xb + (size_t)t0 * D + 32 * c;
            pf[2 * c]     = *(const float4*)p;
            pf[2 * c + 1] = *(const float4*)(p + 4);
        }
    };
    short8 xf[4];
    auto cvt_xf = [&]() {
        #pragma unroll
        for (int c = 0; c < 4; ++c) {
            float4 a = pf[2 * c], bv = pf[2 * c + 1];
            short8 v;
            v[0] = (short)f2bf(a.x);  v[1] = (short)f2bf(a.y);
            v[2] = (short)f2bf(a.z);  v[3] = (short)f2bf(a.w);
            v[4] = (short)f2bf(bv.x); v[5] = (short)f2bf(bv.y);
            v[6] = (short)f2bf(bv.z); v[7] = (short)f2bf(bv.w);
            xf[c] = v;
        }
    };

    float* gxw = gxlds[w];
    f32x4 gxq[4][4];   // gxq[q][s][r] = gx[ts=4s+r][gate q of own cell]+bias

    // gx burst: tile t16 cols = 16*t16+lq, rows = 16 timesteps.
    auto burst = [&]() {
        #pragma unroll
        for (int t16 = 0; t16 < 16; ++t16) {
            f32x4 a = {0.f, 0.f, 0.f, 0.f};
            #pragma unroll
            for (int c = 0; c < 4; ++c) {
                short8 bf = *(const short8*)((char*)wihlds +
                              (16 * t16 + lq) * 256 + (((4 * c + qd) ^ lq) << 4));
                a = __builtin_amdgcn_mfma_f32_16x16x32_bf16(xf[c], bf, a, 0, 0, 0);
            }
            // lane holds rows ts=4qd..4qd+3 of col lq -> contiguous b128
            *(f32x4*)&gxw[t16 * 320 + lq * 20 + 4 * qd] = a;
        }
    };
    auto readback = [&]() {   // same-wave round trip: no barrier
        #pragma unroll
        for (int q = 0; q < 4; ++q)
            #pragma unroll
            for (int s = 0; s < 4; ++s) {
                f32x4 v = *(const f32x4*)&gxw[(4 * q + qd) * 320 + lq * 20 + 4 * s];
                v[0] += bias4[q]; v[1] += bias4[q];
                v[2] += bias4[q]; v[3] += bias4[q];
                gxq[q][s] = v;
            }
    };

    // ---- h0 = 0 (wave-private) ----
    unsigned short* hw = hlds[w];
    if (lane < 32) ((unsigned int*)hw)[lane] = 0u;

    f32x4 accq[16];
    #pragma unroll
    for (int i = 0; i < 16; ++i) accq[i] = (f32x4){0.f, 0.f, 0.f, 0.f};

    // prologue
    issue_pf(0);
    cvt_xf();              // waits HBM once
    issue_pf(TC);          // x(ch1) in flight
    burst();               // gx(ch0) -> gxlds
    readback();            // -> gxq

    float cst = 0.0f, hv = 0.0f;

    for (int ch = 0; ch < NCH; ++ch) {
        #pragma unroll
        for (int tt = 0; tt < TC; ++tt) {
            // A-fragment: rows = h replicas; addr lq-independent (broadcast)
            short8 hfr0 = *(const short8*)((char*)hw + 16 * qd);
            short8 hfr1 = *(const short8*)((char*)hw + 64 + 16 * qd);

            float gv[4];
            #pragma unroll
            for (int q = 0; q < 4; ++q) {
                const float g = gxq[q][tt >> 2][tt & 3];
                #pragma unroll
                for (int d = 0; d < 4; ++d) {
                    const int i = 4 * q + d;
                    accq[i][0] = g;    // C reg0 = gx; rows 1-3 junk (bounded)
                    accq[i] = __builtin_amdgcn_mfma_f32_16x16x32_bf16(
                                  hfr0, whh_f[i][0], accq[i], 0, 0, 0);
                    accq[i] = __builtin_amdgcn_mfma_f32_16x16x32_bf16(
                                  hfr1, whh_f[i][1], accq[i], 0, 0, 0);
                }
                // own gate q sits in tile 4q+qd, reg0: 2-level select
                float v01 = (qd & 1) ? accq[4 * q + 1][0] : accq[4 * q + 0][0];
                float v23 = (qd & 1) ? accq[4 * q + 3][0] : accq[4 * q + 2][0];
                gv[q] = (qd & 2) ? v23 : v01;
            }

            float gi = sigmoidf_(gv[0]);
            float gf = sigmoidf_(gv[1]);
            float gg = tanhf_  (gv[2]);
            float go = sigmoidf_(gv[3]);
            cst = fmaf(gf, cst, gi * gg);
            hv  = go * tanhf_(cst);
            hw[16 * qd + lq] = f2bf(hv);   // in-order LDS: next read sees it
        }

        if (ch + 1 < NCH) {
            cvt_xf();                                   // x(ch+1)
            const int tnext = (ch + 2 < NCH ? ch + 2 : NCH - 1) * TC;
            issue_pf(tnext);                            // x(ch+2)
            burst();                                    // gx(ch+1)
            readback();
        }
    }

    // ---- epilogue (per wave, no block barrier): logits + log_softmax ----
    hfin[w][16 * qd + lq] = hv;
    {
        float l0 = bo[lane], l1 = bo[lane + 64];
        const float* w0 = Wo + (size_t)lane * H;
        const float* w1 = Wo + (size_t)(lane + 64) * H;
        #pragma unroll
        for (int k = 0; k < H; ++k) {
            float rh = fmaxf(hfin[w][k], 0.0f);
            l0 = fmaf(rh, w0[k], l0);
            l1 = fmaf(rh, w1[k], l1);
        }
        float mx = fmaxf(l0, l1);
        #pragma unroll
        for (int sh = 32; sh > 0; sh >>= 1) mx = fmaxf(mx, __shfl_xor(mx, sh));
        float e = __expf(l0 - mx) + __expf(l1 - mx);
        #pragma unroll
        for (int sh = 32; sh > 0; sh >>= 1) e += __shfl_xor(e, sh);
        float lse = mx + __logf(e);
        float* op = out + (size_t)b * O;
        op[lane]      = l0 - lse;
        op[lane + 64] = l1 - lse;
    }
}

extern "C" void kernel_launch(void* const* d_in, const int* in_sizes, int n_in,
                              void* d_out, int out_size, void* d_ws, size_t ws_size,
                              hipStream_t stream) {
    const float* x   = (const float*)d_in[0];
    const float* Wih = (const float*)d_in[1];
    const float* Whh = (const float*)d_in[2];
    const float* bih = (const float*)d_in[3];
    const float* bhh = (const float*)d_in[4];
    const float* Wo  = (const float*)d_in[5];
    const float* bo  = (const float*)d_in[6];
    lstm_fused<<<dim3(NBLK), dim3(256), 0, stream>>>(
        x, Wih, Whh, bih, bhh, Wo, bo, (float*)d_out);
}

// Round 3
// 331.743 us; speedup vs baseline: 1.2019x; 1.2019x over previous
//
#include <hip/hip_runtime.h>
#include <math.h>

// Fused LSTM, bf16 MFMA, WAVE-SPECIALIZED producer/consumer (round 11).
// B=1024,T=256,D=128,H=64,G=256,O=128. 256 blocks x 256 thr (4 waves).
// Block owns 4 batches. NO s_barrier in the 256-step loop.
//   wave 3 (consumer): serial recurrent chain, Whh B-frags in 128 VGPRs.
//     Per step: 2 broadcast ds_read_b128 (h, replicated rows m=4b+rr,
//     pitch 80 shorts -> 2-way banks) -> 32 MFMA (16 tiles x K=64; M-rows
//     = 4 batches x 4 replicas -> 8 MFMA/batch, R8 efficiency) -> lane
//     (qd,lq) reads gate q of batch qd, cell 16s+lq from acc[4q+s] reg0
//     (compile-time indices, NO cross-lane redistribution) -> 4 acts/lane
//     -> 4 ds_write_b16. gx read as 4 prefetched b128/step.
//   waves 0-2 (producers): hold Wih col-tile slices (6/5/5 tiles, <=96
//     VGPRs), stream gx = bias + x.Wih^T for 4 ts/fill into a 4-deep LDS
//     ring (20KB/buf), layout [ts][j(pitch20)][b][q] so consumer reads
//     f32x4 over gates. Sync: LDS atomics fillcnt/freecnt + s_sleep spin.
//     Producers run ~4x faster than consumer -> never starve it.
// R10 lesson: Whh(128)+Wih-path regs on ONE wave spilled to scratch
// (WRITE_SIZE 0.5->65MB). Splitting weight residency across wave roles
// keeps every path under the 256-VGPR architected file.
constexpr int B = 1024, T = 256, D = 128, H = 64, O = 128;
constexpr int BQ = 4;
constexpr int NBLK = B / BQ;     // 256 blocks
constexpr int FT = 4;            // timesteps per fill
constexpr int NF = T / FT;       // 64 fills
constexpr int NBUF = 4;          // ring depth
constexpr int JP = 20;           // j-pitch in dwords (16 data + 4 pad)
constexpr int TSP = 64 * JP + 4; // ts-pitch dwords (pad -> qd spreads banks)
constexpr int BUFSZ = FT * TSP;  // 5136 dwords per buffer

typedef __attribute__((ext_vector_type(8))) short short8;
typedef __attribute__((ext_vector_type(4))) float f32x4;

__device__ __forceinline__ unsigned short f2bf(float f) {
    union { float f; unsigned u; } v; v.f = f;
    return (unsigned short)((v.u + 0x7FFF + ((v.u >> 16) & 1)) >> 16);  // RNE
}
__device__ __forceinline__ float frcp(float x) { return __builtin_amdgcn_rcpf(x); }
__device__ __forceinline__ float sigmoidf_(float x) {
    return frcp(1.0f + __expf(-x));
}
__device__ __forceinline__ float tanhf_(float x) {
    return fmaf(2.0f, frcp(1.0f + __expf(-2.0f * x)), -1.0f);  // overflow-safe
}

// Producer: owns col-tiles [T0, T0+NT). Tile t => gates G=16t+lq, i.e.
// gate-slot q=t>>2 of cells j=16*(t&3)+lq. MFMA A rows m=4*ts'+b.
template<int T0, int NT>
__device__ __forceinline__ void producer_loop(
    const float* __restrict__ x, const float* __restrict__ Wih,
    const float* __restrict__ bih, const float* __restrict__ bhh,
    float* gxb, volatile int* vfree, int* fillcnt, int b0, int lane)
{
    const int lq = lane & 15;
    const int qd = lane >> 4;

    short8 wf[NT][4];
    float  bs[NT];
    #pragma unroll
    for (int ti = 0; ti < NT; ++ti) {
        const int G = 16 * (T0 + ti) + lq;
        #pragma unroll
        for (int c = 0; c < 4; ++c) {
            const float* p = Wih + (size_t)G * D + 32 * c + 8 * qd;
            short8 v;
            #pragma unroll
            for (int j = 0; j < 8; ++j) v[j] = (short)f2bf(p[j]);
            wf[ti][c] = v;
        }
        bs[ti] = bih[G] + bhh[G];
    }

    // A-frag: lane row m=lq -> b=lq&3, ts'=lq>>2; k = 32c+8qd..+7
    const float* xb = x + ((size_t)(b0 + (lq & 3)) * T + (lq >> 2)) * D + 8 * qd;
    float4 pf[4][2];
    auto iload = [&](int f) {
        #pragma unroll
        for (int c = 0; c < 4; ++c) {
            const float* p = xb + (size_t)(FT * f) * D + 32 * c;
            pf[c][0] = *(const float4*)p;
            pf[c][1] = *(const float4*)(p + 4);
        }
    };
    iload(0);

    for (int f = 0; f < NF; ++f) {
        short8 xf[4];
        #pragma unroll
        for (int c = 0; c < 4; ++c) {
            float4 a = pf[c][0], bv = pf[c][1];
            short8 v;
            v[0] = (short)f2bf(a.x);  v[1] = (short)f2bf(a.y);
            v[2] = (short)f2bf(a.z);  v[3] = (short)f2bf(a.w);
            v[4] = (short)f2bf(bv.x); v[5] = (short)f2bf(bv.y);
            v[6] = (short)f2bf(bv.z); v[7] = (short)f2bf(bv.w);
            xf[c] = v;
        }
        if (f + 1 < NF) iload(f + 1);          // HBM latency overlaps spin

        const int epoch = f >> 2;               // reuses of this buffer so far
        while (vfree[f & 3] < epoch) __builtin_amdgcn_s_sleep(2);

        float* buf = gxb + (f & 3) * BUFSZ + qd * TSP + lq * JP;
        #pragma unroll
        for (int ti = 0; ti < NT; ++ti) {
            const int t = T0 + ti;
            f32x4 a = {bs[ti], bs[ti], bs[ti], bs[ti]};   // bias folded in C
            #pragma unroll
            for (int c = 0; c < 4; ++c)
                a = __builtin_amdgcn_mfma_f32_16x16x32_bf16(xf[c], wf[ti][c], a, 0, 0, 0);
            // D rows 4qd+r: ts'=qd, b=r. Write [ts'][j][b][q] scalars.
            float* wp = buf + (16 * (t & 3)) * JP + (t >> 2);
            #pragma unroll
            for (int r = 0; r < 4; ++r) wp[4 * r] = a[r];
        }
        asm volatile("s_waitcnt lgkmcnt(0)" ::: "memory");  // data before flag
        atomicAdd(&fillcnt[f & 3], 1);
    }
}

__global__ __launch_bounds__(256, 1)
void lstm_fused(const float* __restrict__ x, const float* __restrict__ Wih,
                const float* __restrict__ Whh, const float* __restrict__ bih,
                const float* __restrict__ bhh, const float* __restrict__ Wo,
                const float* __restrict__ bo, float* __restrict__ out)
{
    __shared__ float gxb[NBUF * BUFSZ];          // ~80.3 KB gx ring
    __shared__ unsigned short hlds[4 * 80];      // [b][k] pitch 80 shorts
    __shared__ float hfin[4 * 64];               // final h fp32
    __shared__ int fillcnt[NBUF];
    __shared__ int freecnt[NBUF];

    const int tid  = threadIdx.x;
    const int lane = tid & 63;
    const int w    = tid >> 6;
    const int lq   = lane & 15;
    const int qd   = lane >> 4;
    const int b0   = blockIdx.x * BQ;

    if (tid < NBUF) { fillcnt[tid] = 0; freecnt[tid] = 0; }
    if (tid < 160) ((unsigned int*)hlds)[tid] = 0u;   // h0 = 0
    __syncthreads();   // flags + h0 visible; the only pre-epilogue barrier

    if (w == 3) {
        // ================= CONSUMER =================
        short8 whh_f[16][2];   // tile t=4q+s -> gate G=16t+lq, k=32c+8qd..
        #pragma unroll
        for (int t = 0; t < 16; ++t)
            #pragma unroll
            for (int c = 0; c < 2; ++c) {
                const float* p = Whh + (size_t)(16 * t + lq) * H + 32 * c + 8 * qd;
                short8 v;
                #pragma unroll
                for (int j = 0; j < 8; ++j) v[j] = (short)f2bf(p[j]);
                whh_f[t][c] = v;
            }

        // A-frag: m=lq -> b=lq>>2 (replica rr=lq&3 ignored by addressing)
        const char* hbase = (const char*)hlds + (lq >> 2) * 160 + 16 * qd;

        volatile int* vfill = fillcnt;
        f32x4 gxn[4];
        auto wait_fill = [&](int f) {
            const int tgt = 3 * ((f >> 2) + 1);
            while (vfill[f & 3] < tgt) __builtin_amdgcn_s_sleep(2);
        };
        auto pre = [&](int tt) {
            const float* p = gxb + ((tt >> 2) & 3) * BUFSZ + (tt & 3) * TSP +
                             lq * JP + 4 * qd;
            #pragma unroll
            for (int s = 0; s < 4; ++s)
                gxn[s] = *(const f32x4*)(p + s * 16 * JP);
        };

        wait_fill(0);
        pre(0);

        float cst[4] = {0.f, 0.f, 0.f, 0.f};
        float hv4[4];

        for (int tt = 0; tt < T; ++tt) {
            short8 h0 = *(const short8*)hbase;          // old h (reads first)
            short8 h1 = *(const short8*)(hbase + 64);

            #pragma unroll
            for (int s = 0; s < 4; ++s) {
                f32x4 a0 = {0.f,0.f,0.f,0.f}, a1 = a0, a2 = a0, a3 = a0;
                a0 = __builtin_amdgcn_mfma_f32_16x16x32_bf16(h0, whh_f[s][0], a0, 0,0,0);
                a0 = __builtin_amdgcn_mfma_f32_16x16x32_bf16(h1, whh_f[s][1], a0, 0,0,0);
                a1 = __builtin_amdgcn_mfma_f32_16x16x32_bf16(h0, whh_f[4+s][0], a1, 0,0,0);
                a1 = __builtin_amdgcn_mfma_f32_16x16x32_bf16(h1, whh_f[4+s][1], a1, 0,0,0);
                a2 = __builtin_amdgcn_mfma_f32_16x16x32_bf16(h0, whh_f[8+s][0], a2, 0,0,0);
                a2 = __builtin_amdgcn_mfma_f32_16x16x32_bf16(h1, whh_f[8+s][1], a2, 0,0,0);
                a3 = __builtin_amdgcn_mfma_f32_16x16x32_bf16(h0, whh_f[12+s][0], a3, 0,0,0);
                a3 = __builtin_amdgcn_mfma_f32_16x16x32_bf16(h1, whh_f[12+s][1], a3, 0,0,0);

                // D rows 4qd+r = 4b+rr -> b=qd; reg0 = full gate, batch qd
                float gi = sigmoidf_(a0[0] + gxn[s][0]);
                float gf = sigmoidf_(a1[0] + gxn[s][1]);
                float gg = tanhf_  (a2[0] + gxn[s][2]);
                float go = sigmoidf_(a3[0] + gxn[s][3]);
                cst[s] = fmaf(gf, cst[s], gi * gg);
                float hv = go * tanhf_(cst[s]);
                hv4[s] = hv;
                hlds[qd * 80 + 16 * s + lq] = f2bf(hv);  // in-wave order OK
            }

            if ((tt & 3) == 3) {
                asm volatile("s_waitcnt lgkmcnt(0)" ::: "memory");
                atomicAdd(&freecnt[(tt >> 2) & 3], 1);   // release this fill
                if (tt + 1 < T) wait_fill((tt + 1) >> 2);
            }
            if (tt + 1 < T) pre(tt + 1);   // latency hides under next step
        }

        #pragma unroll
        for (int s = 0; s < 4; ++s)
            hfin[qd * 64 + 16 * s + lq] = hv4[s];
    } else if (w == 0) {
        producer_loop<0, 6>(x, Wih, bih, bhh, gxb, freecnt, fillcnt, b0, lane);
    } else if (w == 1) {
        producer_loop<6, 5>(x, Wih, bih, bhh, gxb, freecnt, fillcnt, b0, lane);
    } else {
        producer_loop<11, 5>(x, Wih, bih, bhh, gxb, freecnt, fillcnt, b0, lane);
    }

    __syncthreads();   // hfin ready for all waves

    // ---- epilogue: logits = relu(h) Wo^T + bo ; log_softmax over O=128 ----
    {
        const int m = w;                       // wave w handles batch w
        float l0 = bo[lane], l1 = bo[lane + 64];
        const float* w0 = Wo + (size_t)lane * H;
        const float* w1 = Wo + (size_t)(lane + 64) * H;
        #pragma unroll
        for (int k = 0; k < H; ++k) {
            float rh = fmaxf(hfin[m * 64 + k], 0.0f);
            l0 = fmaf(rh, w0[k], l0);
            l1 = fmaf(rh, w1[k], l1);
        }
        float mx = fmaxf(l0, l1);
        #pragma unroll
        for (int sh = 32; sh > 0; sh >>= 1) mx = fmaxf(mx, __shfl_xor(mx, sh));
        float e = __expf(l0 - mx) + __expf(l1 - mx);
        #pragma unroll
        for (int sh = 32; sh > 0; sh >>= 1) e += __shfl_xor(e, sh);
        float lse = mx + __logf(e);
        float* op = out + (size_t)(b0 + m) * O;
        op[lane]      = l0 - lse;
        op[lane + 64] = l1 - lse;
    }
}

extern "C" void kernel_launch(void* const* d_in, const int* in_sizes, int n_in,
                              void* d_out, int out_size, void* d_ws, size_t ws_size,
                              hipStream_t stream) {
    const float* x   = (const float*)d_in[0];
    const float* Wih = (const float*)d_in[1];
    const float* Whh = (const float*)d_in[2];
    const float* bih = (const float*)d_in[3];
    const float* bhh = (const float*)d_in[4];
    const float* Wo  = (const float*)d_in[5];
    const float* bo  = (const float*)d_in[6];
    lstm_fused<<<dim3(NBLK), dim3(256), 0, stream>>>(
        x, Wih, Whh, bih, bhh, Wo, bo, (float*)d_out);
}

// Round 4
// 302.382 us; speedup vs baseline: 1.3186x; 1.0971x over previous
//
#include <hip/hip_runtime.h>
#include <math.h>

// Fused LSTM, bf16 MFMA, 2 producers + 2 COLUMN-SPLIT consumers (round 12).
// B=1024,T=256,D=128,H=64,G=256,O=128. 256 blocks x 256 thr (4 waves).
// R11 measured: 1-wave consumer (32 MFMA + 20 trans/lane) = 1810 cy/step,
// WORSE than R8's 4-wave barriered 1350. Work concentration cost > sync
// cost. This round splits the consumer in two:
//   waves 2,3 (consumers cw=0,1): col-tiles s in {2cw,2cw+1} -> 8 tiles =
//     16 MFMA/step, acts for 2 cells/lane (10 trans). h double-buffered;
//     per-step handshake via per-wave LDS seq counters (single-writer
//     volatile store + partner spin) -- no s_barrier (producers can't join).
//   waves 0,1 (producers): 8 Wih col-tiles each (128 VGPR frags), stream
//     gx = bias + x.Wih^T into the 4-deep LDS ring (R11-verified layout),
//     fill/free targets doubled (2 producers, 2 consumers).
// Per-consumer-step chain: spin(~120) + h-read(120) + 16 MFMA(~110) +
// acts(~220) + h-half write -> ~650 cy vs R11's 1810.
constexpr int B = 1024, T = 256, D = 128, H = 64, O = 128;
constexpr int BQ = 4;
constexpr int NBLK = B / BQ;     // 256 blocks
constexpr int FT = 4;            // timesteps per fill
constexpr int NF = T / FT;       // 64 fills
constexpr int NBUF = 4;          // ring depth
constexpr int JP = 20;           // j-pitch in dwords (16 data + 4 pad)
constexpr int TSP = 64 * JP + 4; // ts-pitch dwords
constexpr int BUFSZ = FT * TSP;  // 5136 dwords per buffer

typedef __attribute__((ext_vector_type(8))) short short8;
typedef __attribute__((ext_vector_type(4))) float f32x4;

__device__ __forceinline__ unsigned short f2bf(float f) {
    union { float f; unsigned u; } v; v.f = f;
    return (unsigned short)((v.u + 0x7FFF + ((v.u >> 16) & 1)) >> 16);  // RNE
}
__device__ __forceinline__ float frcp(float x) { return __builtin_amdgcn_rcpf(x); }
__device__ __forceinline__ float sigmoidf_(float x) {
    return frcp(1.0f + __expf(-x));
}
__device__ __forceinline__ float tanhf_(float x) {
    return fmaf(2.0f, frcp(1.0f + __expf(-2.0f * x)), -1.0f);  // overflow-safe
}

// Producer: owns col-tiles [T0, T0+NT). Tile t => gates G=16t+lq, i.e.
// gate-slot q=t>>2 of cells j=16*(t&3)+lq. MFMA A rows m=4*ts'+b.
template<int T0, int NT>
__device__ __forceinline__ void producer_loop(
    const float* __restrict__ x, const float* __restrict__ Wih,
    const float* __restrict__ bih, const float* __restrict__ bhh,
    float* gxb, volatile int* vfree, int* fillcnt, int b0, int lane)
{
    const int lq = lane & 15;
    const int qd = lane >> 4;

    short8 wf[NT][4];
    float  bs[NT];
    #pragma unroll
    for (int ti = 0; ti < NT; ++ti) {
        const int G = 16 * (T0 + ti) + lq;
        #pragma unroll
        for (int c = 0; c < 4; ++c) {
            const float* p = Wih + (size_t)G * D + 32 * c + 8 * qd;
            short8 v;
            #pragma unroll
            for (int j = 0; j < 8; ++j) v[j] = (short)f2bf(p[j]);
            wf[ti][c] = v;
        }
        bs[ti] = bih[G] + bhh[G];
    }

    // A-frag: lane row m=lq -> b=lq&3, ts'=lq>>2; k = 32c+8qd..+7
    const float* xb = x + ((size_t)(b0 + (lq & 3)) * T + (lq >> 2)) * D + 8 * qd;
    float4 pf[4][2];
    auto iload = [&](int f) {
        #pragma unroll
        for (int c = 0; c < 4; ++c) {
            const float* p = xb + (size_t)(FT * f) * D + 32 * c;
            pf[c][0] = *(const float4*)p;
            pf[c][1] = *(const float4*)(p + 4);
        }
    };
    iload(0);

    for (int f = 0; f < NF; ++f) {
        short8 xf[4];
        #pragma unroll
        for (int c = 0; c < 4; ++c) {
            float4 a = pf[c][0], bv = pf[c][1];
            short8 v;
            v[0] = (short)f2bf(a.x);  v[1] = (short)f2bf(a.y);
            v[2] = (short)f2bf(a.z);  v[3] = (short)f2bf(a.w);
            v[4] = (short)f2bf(bv.x); v[5] = (short)f2bf(bv.y);
            v[6] = (short)f2bf(bv.z); v[7] = (short)f2bf(bv.w);
            xf[c] = v;
        }
        if (f + 1 < NF) iload(f + 1);          // HBM latency overlaps spin

        const int epoch = f >> 2;               // buffer reuse count
        while (vfree[f & 3] < 2 * epoch) __builtin_amdgcn_s_sleep(2);

        float* buf = gxb + (f & 3) * BUFSZ + qd * TSP + lq * JP;
        #pragma unroll
        for (int ti = 0; ti < NT; ++ti) {
            const int t = T0 + ti;
            f32x4 a = {bs[ti], bs[ti], bs[ti], bs[ti]};   // bias folded in C
            #pragma unroll
            for (int c = 0; c < 4; ++c)
                a = __builtin_amdgcn_mfma_f32_16x16x32_bf16(xf[c], wf[ti][c], a, 0, 0, 0);
            // D rows 4qd+r: ts'=qd, b=r. Layout [ts][j:JP][q + 4b].
            float* wp = buf + (16 * (t & 3)) * JP + (t >> 2);
            #pragma unroll
            for (int r = 0; r < 4; ++r) wp[4 * r] = a[r];
        }
        asm volatile("s_waitcnt lgkmcnt(0)" ::: "memory");  // data before flag
        atomicAdd(&fillcnt[f & 3], 1);
    }
}

__global__ __launch_bounds__(256, 1)
void lstm_fused(const float* __restrict__ x, const float* __restrict__ Wih,
                const float* __restrict__ Whh, const float* __restrict__ bih,
                const float* __restrict__ bhh, const float* __restrict__ Wo,
                const float* __restrict__ bo, float* __restrict__ out)
{
    __shared__ float gxb[NBUF * BUFSZ];          // ~80.3 KB gx ring
    __shared__ unsigned short hlds[2 * 320];     // [buf][b][k] pitch 80
    __shared__ float hfin[4 * 64];               // final h fp32
    __shared__ int fillcnt[NBUF];
    __shared__ int freecnt[NBUF];
    __shared__ int cseq[2];                      // consumer handshake flags

    const int tid  = threadIdx.x;
    const int lane = tid & 63;
    const int w    = tid >> 6;
    const int lq   = lane & 15;
    const int qd   = lane >> 4;
    const int b0   = blockIdx.x * BQ;

    if (tid < NBUF) { fillcnt[tid] = 0; freecnt[tid] = 0; }
    if (tid < 2) cseq[tid] = 0;
    if (tid < 160) ((unsigned int*)hlds)[tid] = 0u;   // h0 = 0 (buffer 0)
    __syncthreads();   // flags + h0 visible; only pre-epilogue barrier

    float hv[2] = {0.f, 0.f};
    int   cwg = -1;

    if (w >= 2) {
        // ================= CONSUMER cw =================
        const int cw = w - 2;   cwg = cw;
        // B-frags: tiles 4q + (2cw+si) -> gate rows G = 64q+32cw+16si+lq
        short8 whh_f[4][2][2];
        #pragma unroll
        for (int q = 0; q < 4; ++q)
            #pragma unroll
            for (int si = 0; si < 2; ++si)
                #pragma unroll
                for (int c = 0; c < 2; ++c) {
                    const int G = 64 * q + 32 * cw + 16 * si + lq;
                    const float* p = Whh + (size_t)G * H + 32 * c + 8 * qd;
                    short8 v;
                    #pragma unroll
                    for (int j = 0; j < 8; ++j) v[j] = (short)f2bf(p[j]);
                    whh_f[q][si][c] = v;
                }

        volatile int* vfill = fillcnt;
        volatile int* vseq  = cseq;
        f32x4 gxn[2];
        auto wait_fill = [&](int f) {
            const int tgt = 2 * ((f >> 2) + 1);          // 2 producers
            while (vfill[f & 3] < tgt) __builtin_amdgcn_s_sleep(2);
        };
        auto pre = [&](int tt) {
            const float* p = gxb + ((tt >> 2) & 3) * BUFSZ + (tt & 3) * TSP + 4 * qd;
            gxn[0] = *(const f32x4*)(p + (16 * (2 * cw + 0) + lq) * JP);
            gxn[1] = *(const f32x4*)(p + (16 * (2 * cw + 1) + lq) * JP);
        };

        wait_fill(0);
        pre(0);

        float cst[2] = {0.f, 0.f};
        const int hb = (lq >> 2) * 80 + 8 * qd;   // shorts; A row m=lq -> b=lq>>2

        for (int tt = 0; tt < T; ++tt) {
            const unsigned short* hc = hlds + (tt & 1) * 320;
            short8 h0 = *(const short8*)(hc + hb);          // cells  0-31
            short8 h1 = *(const short8*)(hc + hb + 32);     // cells 32-63

            f32x4 acc[4][2];
            #pragma unroll
            for (int q = 0; q < 4; ++q)
                #pragma unroll
                for (int si = 0; si < 2; ++si) {
                    const float g = gxn[si][q];
                    f32x4 a = {g, g, g, g};
                    a = __builtin_amdgcn_mfma_f32_16x16x32_bf16(h0, whh_f[q][si][0], a, 0, 0, 0);
                    a = __builtin_amdgcn_mfma_f32_16x16x32_bf16(h1, whh_f[q][si][1], a, 0, 0, 0);
                    acc[q][si] = a;
                }

            unsigned short* hn = hlds + ((tt + 1) & 1) * 320;
            #pragma unroll
            for (int si = 0; si < 2; ++si) {
                // D rows 4qd+r all = batch qd (replicas): reg0 = full gate
                float gi = sigmoidf_(acc[0][si][0]);
                float gf = sigmoidf_(acc[1][si][0]);
                float gg = tanhf_  (acc[2][si][0]);
                float go = sigmoidf_(acc[3][si][0]);
                cst[si] = fmaf(gf, cst[si], gi * gg);
                hv[si]  = go * tanhf_(cst[si]);
                hn[qd * 80 + 16 * (2 * cw + si) + lq] = f2bf(hv[si]);
            }

            asm volatile("s_waitcnt lgkmcnt(0)" ::: "memory");  // h before flag
            if (lane == 0) ((volatile int*)cseq)[cw] = tt + 1;  // single writer

            if ((tt & 3) == 3) {                 // buffer consumed
                atomicAdd(&freecnt[(tt >> 2) & 3], 1);
                if (tt + 1 < T) wait_fill((tt + 1) >> 2);
            }
            if (tt + 1 < T) pre(tt + 1);         // gx prefetch during wait

            while (vseq[1 - cw] < tt + 1) {}     // partner handshake
            asm volatile("" ::: "memory");       // no hoisting above spin
        }
    } else if (w == 0) {
        producer_loop<0, 8>(x, Wih, bih, bhh, gxb, freecnt, fillcnt, b0, lane);
    } else {
        producer_loop<8, 8>(x, Wih, bih, bhh, gxb, freecnt, fillcnt, b0, lane);
    }

    if (cwg >= 0) {
        #pragma unroll
        for (int si = 0; si < 2; ++si)
            hfin[qd * 64 + 16 * (2 * cwg + si) + lq] = hv[si];
    }
    __syncthreads();   // hfin ready for all waves

    // ---- epilogue: logits = relu(h) Wo^T + bo ; log_softmax over O=128 ----
    {
        const int m = w;                       // wave w handles batch w
        float l0 = bo[lane], l1 = bo[lane + 64];
        const float* w0 = Wo + (size_t)lane * H;
        const float* w1 = Wo + (size_t)(lane + 64) * H;
        #pragma unroll
        for (int k = 0; k < H; ++k) {
            float rh = fmaxf(hfin[m * 64 + k], 0.0f);
            l0 = fmaf(rh, w0[k], l0);
            l1 = fmaf(rh, w1[k], l1);
        }
        float mx = fmaxf(l0, l1);
        #pragma unroll
        for (int sh = 32; sh > 0; sh >>= 1) mx = fmaxf(mx, __shfl_xor(mx, sh));
        float e = __expf(l0 - mx) + __expf(l1 - mx);
        #pragma unroll
        for (int sh = 32; sh > 0; sh >>= 1) e += __shfl_xor(e, sh);
        float lse = mx + __logf(e);
        float* op = out + (size_t)(b0 + m) * O;
        op[lane]      = l0 - lse;
        op[lane + 64] = l1 - lse;
    }
}

extern "C" void kernel_launch(void* const* d_in, const int* in_sizes, int n_in,
                              void* d_out, int out_size, void* d_ws, size_t ws_size,
                              hipStream_t stream) {
    const float* x   = (const float*)d_in[0];
    const float* Wih = (const float*)d_in[1];
    const float* Whh = (const float*)d_in[2];
    const float* bih = (const float*)d_in[3];
    const float* bhh = (const float*)d_in[4];
    const float* Wo  = (const float*)d_in[5];
    const float* bo  = (const float*)d_in[6];
    lstm_fused<<<dim3(NBLK), dim3(256), 0, stream>>>(
        x, Wih, Whh, bih, bhh, Wo, bo, (float*)d_out);
}